// Round 2
// baseline (299.036 us; speedup 1.0000x reference)
//
#include <hip/hip_runtime.h>
#include <stdint.h>

#define H 256
#define EPS 1e-8f
#define NBINS 512          // skey space: (bucket&7)<<6 | bucket>>3, bucket = c>>7 < 392

typedef __bf16 bf16x8 __attribute__((ext_vector_type(8)));
typedef float  f32x4  __attribute__((ext_vector_type(4)));

__device__ __forceinline__ unsigned short f2bf(float f) {
  unsigned u = __builtin_bit_cast(unsigned, f);
  u += 0x7FFFu + ((u >> 16) & 1u);            // round-to-nearest-even
  return (unsigned short)(u >> 16);
}
__device__ __forceinline__ float bflo(unsigned u){ return __builtin_bit_cast(float, u << 16); }
__device__ __forceinline__ float bfhi(unsigned u){ return __builtin_bit_cast(float, u & 0xFFFF0000u); }

__device__ __forceinline__ void g2l16(const void* g, void* l) {
  __builtin_amdgcn_global_load_lds((__attribute__((address_space(1))) void*)g,
                                   (__attribute__((address_space(3))) void*)l, 16, 0, 0);
}

__device__ __forceinline__ int skey_of(int c) {
  int b = c >> 7;
  return ((b & 7) << 6) | (b >> 3);
}

// fp32 -> bf16 for emb (zero-padded to Mp rows), W1, W2 in ONE launch.
// Also zeroes the 512-bin histogram (used by hist_kernel later in the stream).
__global__ __launch_bounds__(256) void conv_all_kernel(
    const float* __restrict__ emb, const float* __restrict__ W1, const float* __restrict__ W2,
    unsigned short* __restrict__ embB, unsigned short* __restrict__ w1B,
    unsigned short* __restrict__ w2B, int NH, int MpH, int* __restrict__ counts) {
  int t = blockIdx.x * 256 + threadIdx.x;
  if (t < NBINS) counts[t] = 0;
  int i = t * 4;
  const int HH = H * H;
  const float* src; unsigned short* dst; int idx; int valid;
  if (i < MpH)            { src = emb; dst = embB; idx = i;            valid = NH; }
  else if (i < MpH + HH)  { src = W1;  dst = w1B;  idx = i - MpH;      valid = HH; }
  else                    { src = W2;  dst = w2B;  idx = i - MpH - HH; valid = HH; }
  float4 v = make_float4(0.f, 0.f, 0.f, 0.f);
  if (idx < valid) v = *(const float4*)(src + idx);
  ushort4 o;
  o.x = f2bf(v.x); o.y = f2bf(v.y); o.z = f2bf(v.z); o.w = f2bf(v.w);
  *(ushort4*)(dst + idx) = o;
}

// C[Mp,256] = act(A[Mp,256] @ B[256,256]^T + bias), bf16 in/out, fp32 accum.
template<bool RELU>
__global__ __launch_bounds__(256) void gemm_bt_kernel(
    const unsigned short* __restrict__ A,
    const unsigned short* __restrict__ B,
    const float* __restrict__ bias,
    unsigned short* __restrict__ C) {
  __shared__ unsigned short sA[128 * 32];
  __shared__ unsigned short sB[128 * 32];
  const int tid  = threadIdx.x;
  const int wave = tid >> 6, lane = tid & 63;
  const int quad = lane >> 4, l16 = lane & 15;
  const int wm = wave & 1, wn = wave >> 1;
  const size_t bm = blockIdx.x, bn = blockIdx.y;

  const int srow0 = (wave * 2 + 0) * 16 + (lane >> 2);
  const int srow1 = (wave * 2 + 1) * 16 + (lane >> 2);
  const int kch   = (lane & 3) * 8;
  const unsigned short* gA0 = A + ((bm * 128 + srow0) * H + kch);
  const unsigned short* gA1 = A + ((bm * 128 + srow1) * H + kch);
  const unsigned short* gB0 = B + ((bn * 128 + srow0) * H + kch);
  const unsigned short* gB1 = B + ((bn * 128 + srow1) * H + kch);
  unsigned short* lA0 = sA + (wave * 2 + 0) * 512 + lane * 8;
  unsigned short* lA1 = sA + (wave * 2 + 1) * 512 + lane * 8;
  unsigned short* lB0 = sB + (wave * 2 + 0) * 512 + lane * 8;
  unsigned short* lB1 = sB + (wave * 2 + 1) * 512 + lane * 8;

  f32x4 acc[4][4];
#pragma unroll
  for (int i = 0; i < 4; i++)
#pragma unroll
    for (int j = 0; j < 4; j++) acc[i][j] = (f32x4){0.f, 0.f, 0.f, 0.f};

#pragma unroll
  for (int kk = 0; kk < H / 32; ++kk) {
    const int k0 = kk * 32;
    if (kk) __syncthreads();
    g2l16(gA0 + k0, lA0);
    g2l16(gA1 + k0, lA1);
    g2l16(gB0 + k0, lB0);
    g2l16(gB1 + k0, lB1);
    __syncthreads();

    bf16x8 af[4], bfr[4];
#pragma unroll
    for (int i = 0; i < 4; i++)
      af[i] = *(const bf16x8*)(sA + ((wm * 64 + i * 16 + l16) * 32 + quad * 8));
#pragma unroll
    for (int j = 0; j < 4; j++)
      bfr[j] = *(const bf16x8*)(sB + ((wn * 64 + j * 16 + l16) * 32 + quad * 8));
#pragma unroll
    for (int i = 0; i < 4; i++)
#pragma unroll
      for (int j = 0; j < 4; j++)
        acc[i][j] = __builtin_amdgcn_mfma_f32_16x16x32_bf16(af[i], bfr[j], acc[i][j], 0, 0, 0);
  }

  const int row_base = (int)bm * 128 + wm * 64;
  const int col_base = (int)bn * 128 + wn * 64;
#pragma unroll
  for (int j = 0; j < 4; j++) {
    const int col = col_base + j * 16 + l16;
    const float bv = bias[col];
#pragma unroll
    for (int i = 0; i < 4; i++) {
#pragma unroll
      for (int r = 0; r < 4; r++) {
        const int row = row_base + i * 16 + quad * 4 + r;
        float v = acc[i][j][r] + bv;
        if (RELU) v = fmaxf(v, 0.f);
        C[(size_t)row * H + col] = f2bf(v);
      }
    }
  }
}

__global__ __launch_bounds__(256) void rownorm_kernel(
    const unsigned short* __restrict__ g, float* __restrict__ rn, int n) {
  int row = blockIdx.x * 4 + (threadIdx.x >> 6);
  if (row >= n) return;
  int lane = threadIdx.x & 63;
  uint2 a = ((const uint2*)(g + (size_t)row * H))[lane];
  float x0 = bflo(a.x), x1 = bfhi(a.x), x2 = bflo(a.y), x3 = bfhi(a.y);
  float ss = x0 * x0 + x1 * x1 + x2 * x2 + x3 * x3;
#pragma unroll
  for (int off = 32; off; off >>= 1) ss += __shfl_down(ss, off, 64);
  if (lane == 0) rn[row] = 1.f / fmaxf(sqrtf(ss), EPS);
}

// ---- edge counting-sort by XCD-affinity bucket key ----
__global__ __launch_bounds__(256) void hist_kernel(
    const int* __restrict__ ei, int E, int* __restrict__ counts) {
  __shared__ int h[NBINS];
  for (int i = threadIdx.x; i < NBINS; i += 256) h[i] = 0;
  __syncthreads();
  const int stride = gridDim.x * 256;
  for (int e = blockIdx.x * 256 + threadIdx.x; e < E; e += stride)
    atomicAdd(&h[skey_of(ei[e])], 1);
  __syncthreads();
  for (int i = threadIdx.x; i < NBINS; i += 256)
    if (h[i]) atomicAdd(&counts[i], h[i]);
}

__global__ __launch_bounds__(512) void scan_kernel(
    const int* __restrict__ counts, int* __restrict__ offsets, int* __restrict__ cursor) {
  __shared__ int s[NBINS];
  const int t = threadIdx.x;
  const int my = counts[t];
  s[t] = my;
  __syncthreads();
#pragma unroll
  for (int d = 1; d < NBINS; d <<= 1) {
    int v = (t >= d) ? s[t - d] : 0;
    __syncthreads();
    s[t] += v;
    __syncthreads();
  }
  const int excl = s[t] - my;
  offsets[t] = excl;
  cursor[t]  = excl;
  if (t == NBINS - 1) offsets[NBINS] = s[t];
}

__global__ __launch_bounds__(256) void scatter_kernel(
    const int* __restrict__ ei, int E, int* __restrict__ cursor, int4* __restrict__ sorted) {
  int e = blockIdx.x * 256 + threadIdx.x;
  if (e >= E) return;
  int c = ei[e], r = ei[E + e];
  int pos = atomicAdd(&cursor[skey_of(c)], 1);
  sorted[pos] = make_int4(c, r, e, 0);
}

// one wave per 4 edges; blockIdx%8 == XCD-group -> c-side rows stay L2-resident
__global__ __launch_bounds__(256) void edge_cos_kernel(
    const int4* __restrict__ sorted, const int* __restrict__ offsets,
    const unsigned short* __restrict__ g, const float* __restrict__ rn,
    float* __restrict__ out) {
  const int lane = threadIdx.x & 63;
  const int wave = threadIdx.x >> 6;
  const int grp  = blockIdx.x & 7;
  const int wgw  = ((blockIdx.x >> 3) << 2) + wave;   // 0..1023 within group
  const int gs = offsets[grp << 6];
  const int ge = offsets[(grp + 1) << 6];

  for (int e0 = gs + wgw * 4; e0 < ge; e0 += 4096) {
    const int nv = min(4, ge - e0);
    int4 ed[4];
#pragma unroll
    for (int u = 0; u < 4; u++)
      ed[u] = (u < nv) ? sorted[e0 + u] : make_int4(0, 0, 0, 0);

    uint2 va[4], vb[4];
#pragma unroll
    for (int u = 0; u < 4; u++) {
      va[u] = ((const uint2*)(g + (size_t)ed[u].x * H))[lane];
      vb[u] = ((const uint2*)(g + (size_t)ed[u].y * H))[lane];
    }
    float d0, d1, d2, d3;
    float* dp[4] = {&d0, &d1, &d2, &d3};
#pragma unroll
    for (int u = 0; u < 4; u++) {
      uint2 a = va[u], b = vb[u];
      *dp[u] = bflo(a.x) * bflo(b.x) + bfhi(a.x) * bfhi(b.x) +
               bflo(a.y) * bflo(b.y) + bfhi(a.y) * bfhi(b.y);
    }
#pragma unroll
    for (int off = 1; off < 64; off <<= 1) {
      d0 += __shfl_xor(d0, off, 64);
      d1 += __shfl_xor(d1, off, 64);
      d2 += __shfl_xor(d2, off, 64);
      d3 += __shfl_xor(d3, off, 64);
    }
    // lane u stores edge u (dot value is in all lanes after xor-butterfly)
    if (lane == 0 && 0 < nv) out[ed[0].z] = d0 * rn[ed[0].x] * rn[ed[0].y];
    if (lane == 1 && 1 < nv) out[ed[1].z] = d1 * rn[ed[1].x] * rn[ed[1].y];
    if (lane == 2 && 2 < nv) out[ed[2].z] = d2 * rn[ed[2].x] * rn[ed[2].y];
    if (lane == 3 && 3 < nv) out[ed[3].z] = d3 * rn[ed[3].x] * rn[ed[3].y];
  }
}

extern "C" void kernel_launch(void* const* d_in, const int* in_sizes, int n_in,
                              void* d_out, int out_size, void* d_ws, size_t ws_size,
                              hipStream_t stream) {
  const float* emb = (const float*)d_in[0];
  const int*   ei  = (const int*)d_in[1];
  const float* W1  = (const float*)d_in[2];
  const float* b1  = (const float*)d_in[3];
  const float* W2  = (const float*)d_in[4];
  const float* b2  = (const float*)d_in[5];
  float* out = (float*)d_out;

  const int NH = in_sizes[0];
  const int N  = NH / H;
  const int E  = in_sizes[1] / 2;
  const int Mp = ((N + 127) / 128) * 128;
  const int MpH = Mp * H;
  const int HH  = H * H;

  char* ws = (char*)d_ws;
  unsigned short* embB = (unsigned short*)ws; ws += (size_t)MpH * 2;
  unsigned short* hB   = (unsigned short*)ws; ws += (size_t)MpH * 2;   // dead after gemm2
  unsigned short* gB   = (unsigned short*)ws; ws += (size_t)MpH * 2;
  unsigned short* w1B  = (unsigned short*)ws; ws += (size_t)HH * 2;
  unsigned short* w2B  = (unsigned short*)ws; ws += (size_t)HH * 2;
  float* rn            = (float*)ws;          ws += (size_t)N * 4;
  int* counts          = (int*)ws;            ws += NBINS * 4;
  int* offsets         = (int*)ws;            ws += (NBINS + 1) * 4;
  int* cursor          = (int*)ws;            ws += NBINS * 4;
  int4* sorted = (int4*)hB;                   // alias: hB dead once gemm2 done

  const int convTotal = (MpH + 2 * HH) / 4;
  conv_all_kernel<<<(convTotal + 255) / 256, 256, 0, stream>>>(
      emb, W1, W2, embB, w1B, w2B, NH, MpH, counts);

  dim3 ggrid(Mp / 128, H / 128);
  gemm_bt_kernel<true ><<<ggrid, 256, 0, stream>>>(embB, w1B, b1, hB);
  gemm_bt_kernel<false><<<ggrid, 256, 0, stream>>>(hB, w2B, b2, gB);

  rownorm_kernel<<<(N + 3) / 4, 256, 0, stream>>>(gB, rn, N);

  hist_kernel<<<64, 256, 0, stream>>>(ei, E, counts);
  scan_kernel<<<1, 512, 0, stream>>>(counts, offsets, cursor);
  scatter_kernel<<<(E + 255) / 256, 256, 0, stream>>>(ei, E, cursor, sorted);

  edge_cos_kernel<<<2048, 256, 0, stream>>>(sorted, offsets, gB, rn, out);
}

// Round 3
// 285.625 us; speedup vs baseline: 1.0470x; 1.0470x over previous
//
#include <hip/hip_runtime.h>
#include <stdint.h>

#define H 256
#define NBINS 512          // skey space: (bucket&7)<<6 | bucket>>3, bucket = c>>7 < 392
#define NB 64              // blocks in hist/scatter (each owns E/NB contiguous edges)

typedef __bf16 bf16x8 __attribute__((ext_vector_type(8)));
typedef float  f32x4  __attribute__((ext_vector_type(4)));

__device__ __forceinline__ unsigned short f2bf(float f) {
  unsigned u = __builtin_bit_cast(unsigned, f);
  u += 0x7FFFu + ((u >> 16) & 1u);            // round-to-nearest-even
  return (unsigned short)(u >> 16);
}
__device__ __forceinline__ float bflo(unsigned u){ return __builtin_bit_cast(float, u << 16); }
__device__ __forceinline__ float bfhi(unsigned u){ return __builtin_bit_cast(float, u & 0xFFFF0000u); }

__device__ __forceinline__ void g2l16(const void* g, void* l) {
  __builtin_amdgcn_global_load_lds((__attribute__((address_space(1))) void*)g,
                                   (__attribute__((address_space(3))) void*)l, 16, 0, 0);
}

__device__ __forceinline__ int skey_of(int c) {
  int b = c >> 7;
  return ((b & 7) << 6) | (b >> 3);
}

// fp32 -> bf16 for emb (zero-padded to Mp rows), W1, W2 in ONE launch.
// Also zeroes ssq[] (accumulated by gemm2's epilogue later in the stream).
__global__ __launch_bounds__(256) void conv_all_kernel(
    const float* __restrict__ emb, const float* __restrict__ W1, const float* __restrict__ W2,
    unsigned short* __restrict__ embB, unsigned short* __restrict__ w1B,
    unsigned short* __restrict__ w2B, int NH, int MpH, float* __restrict__ ssq, int Mp) {
  int t = blockIdx.x * 256 + threadIdx.x;
  if (t < Mp) ssq[t] = 0.f;
  int i = t * 4;
  const int HH = H * H;
  const float* src; unsigned short* dst; int idx; int valid;
  if (i < MpH)            { src = emb; dst = embB; idx = i;            valid = NH; }
  else if (i < MpH + HH)  { src = W1;  dst = w1B;  idx = i - MpH;      valid = HH; }
  else                    { src = W2;  dst = w2B;  idx = i - MpH - HH; valid = HH; }
  float4 v = make_float4(0.f, 0.f, 0.f, 0.f);
  if (idx < valid) v = *(const float4*)(src + idx);
  ushort4 o;
  o.x = f2bf(v.x); o.y = f2bf(v.y); o.z = f2bf(v.z); o.w = f2bf(v.w);
  *(ushort4*)(dst + idx) = o;
}

// C[Mp,256] = act(A[Mp,256] @ B[256,256]^T + bias), bf16 in/out, fp32 accum.
// NORM: atomically accumulate per-row sum-of-squares of the (pre-cast) outputs.
template<bool RELU, bool NORM>
__global__ __launch_bounds__(256) void gemm_bt_kernel(
    const unsigned short* __restrict__ A,
    const unsigned short* __restrict__ B,
    const float* __restrict__ bias,
    unsigned short* __restrict__ C,
    float* __restrict__ ssq) {
  __shared__ unsigned short sA[128 * 32];
  __shared__ unsigned short sB[128 * 32];
  const int tid  = threadIdx.x;
  const int wave = tid >> 6, lane = tid & 63;
  const int quad = lane >> 4, l16 = lane & 15;
  const int wm = wave & 1, wn = wave >> 1;
  const size_t bm = blockIdx.x, bn = blockIdx.y;

  const int srow0 = (wave * 2 + 0) * 16 + (lane >> 2);
  const int srow1 = (wave * 2 + 1) * 16 + (lane >> 2);
  const int kch   = (lane & 3) * 8;
  const unsigned short* gA0 = A + ((bm * 128 + srow0) * H + kch);
  const unsigned short* gA1 = A + ((bm * 128 + srow1) * H + kch);
  const unsigned short* gB0 = B + ((bn * 128 + srow0) * H + kch);
  const unsigned short* gB1 = B + ((bn * 128 + srow1) * H + kch);
  unsigned short* lA0 = sA + (wave * 2 + 0) * 512 + lane * 8;
  unsigned short* lA1 = sA + (wave * 2 + 1) * 512 + lane * 8;
  unsigned short* lB0 = sB + (wave * 2 + 0) * 512 + lane * 8;
  unsigned short* lB1 = sB + (wave * 2 + 1) * 512 + lane * 8;

  f32x4 acc[4][4];
#pragma unroll
  for (int i = 0; i < 4; i++)
#pragma unroll
    for (int j = 0; j < 4; j++) acc[i][j] = (f32x4){0.f, 0.f, 0.f, 0.f};

#pragma unroll
  for (int kk = 0; kk < H / 32; ++kk) {
    const int k0 = kk * 32;
    if (kk) __syncthreads();
    g2l16(gA0 + k0, lA0);
    g2l16(gA1 + k0, lA1);
    g2l16(gB0 + k0, lB0);
    g2l16(gB1 + k0, lB1);
    __syncthreads();

    bf16x8 af[4], bfr[4];
#pragma unroll
    for (int i = 0; i < 4; i++)
      af[i] = *(const bf16x8*)(sA + ((wm * 64 + i * 16 + l16) * 32 + quad * 8));
#pragma unroll
    for (int j = 0; j < 4; j++)
      bfr[j] = *(const bf16x8*)(sB + ((wn * 64 + j * 16 + l16) * 32 + quad * 8));
#pragma unroll
    for (int i = 0; i < 4; i++)
#pragma unroll
      for (int j = 0; j < 4; j++)
        acc[i][j] = __builtin_amdgcn_mfma_f32_16x16x32_bf16(af[i], bfr[j], acc[i][j], 0, 0, 0);
  }

  // epilogue: C/D layout col=lane&15, row=quad*4+reg (m89/m91-verified)
  const int row_base = (int)bm * 128 + wm * 64;
  const int col_base = (int)bn * 128 + wn * 64;
  float p[4][4];                 // [i][r] partial row sum-of-squares over this block's cols
  if (NORM) {
#pragma unroll
    for (int i = 0; i < 4; i++)
#pragma unroll
      for (int r = 0; r < 4; r++) p[i][r] = 0.f;
  }
#pragma unroll
  for (int j = 0; j < 4; j++) {
    const int col = col_base + j * 16 + l16;
    const float bv = bias[col];
#pragma unroll
    for (int i = 0; i < 4; i++) {
#pragma unroll
      for (int r = 0; r < 4; r++) {
        const int row = row_base + i * 16 + quad * 4 + r;
        float v = acc[i][j][r] + bv;
        if (RELU) v = fmaxf(v, 0.f);
        if (NORM) p[i][r] += v * v;
        C[(size_t)row * H + col] = f2bf(v);
      }
    }
  }
  if (NORM) {
#pragma unroll
    for (int i = 0; i < 4; i++) {
#pragma unroll
      for (int r = 0; r < 4; r++) {
        float s = p[i][r];
#pragma unroll
        for (int off = 1; off < 16; off <<= 1) s += __shfl_xor(s, off, 64);
        if (l16 == 0) atomicAdd(&ssq[row_base + i * 16 + quad * 4 + r], s);
      }
    }
  }
}

// ---- deterministic counting-sort: LDS hist -> scan -> LDS-cursor scatter ----
__global__ __launch_bounds__(256) void hist_kernel(
    const int* __restrict__ ei, int E, int* __restrict__ blockHist) {
  __shared__ int h[NBINS];
  for (int i = threadIdx.x; i < NBINS; i += 256) h[i] = 0;
  __syncthreads();
  const int chunk = (E + NB - 1) / NB;
  const int start = blockIdx.x * chunk, end = min(E, start + chunk);
  for (int e = start + threadIdx.x; e < end; e += 256)
    atomicAdd(&h[skey_of(ei[e])], 1);
  __syncthreads();
  for (int i = threadIdx.x; i < NBINS; i += 256)
    blockHist[i * NB + blockIdx.x] = h[i];
}

__global__ __launch_bounds__(512) void scan_kernel(
    const int* __restrict__ blockHist, int* __restrict__ blockCur,
    int* __restrict__ offsets) {
  __shared__ int s[NBINS];
  const int t = threadIdx.x;           // bin
  int run = 0;
#pragma unroll 1
  for (int b = 0; b < NB; ++b) {
    int v = blockHist[t * NB + b];
    blockCur[t * NB + b] = run;        // block-local prefix within bin
    run += v;
  }
  const int my = run;
  s[t] = my;
  __syncthreads();
#pragma unroll
  for (int d = 1; d < NBINS; d <<= 1) {
    int v = (t >= d) ? s[t - d] : 0;
    __syncthreads();
    s[t] += v;
    __syncthreads();
  }
  const int excl = s[t] - my;
  offsets[t] = excl;
  if (t == NBINS - 1) offsets[NBINS] = s[t];
#pragma unroll 1
  for (int b = 0; b < NB; ++b) blockCur[t * NB + b] += excl;
}

__global__ __launch_bounds__(256) void scatter_kernel(
    const int* __restrict__ ei, int E, const int* __restrict__ blockCur,
    int4* __restrict__ sorted) {
  __shared__ int cur[NBINS];
  for (int i = threadIdx.x; i < NBINS; i += 256)
    cur[i] = blockCur[i * NB + blockIdx.x];
  __syncthreads();
  const int chunk = (E + NB - 1) / NB;
  const int start = blockIdx.x * chunk, end = min(E, start + chunk);
  for (int e = start + threadIdx.x; e < end; e += 256) {
    int c = ei[e], r = ei[E + e];
    int pos = atomicAdd(&cur[skey_of(c)], 1);   // LDS atomic; disjoint output ranges per block
    sorted[pos] = make_int4(c, r, e, 0);
  }
}

// one wave per 4 edges; blockIdx%8 == XCD-group -> c-side rows stay L2-resident
__global__ __launch_bounds__(256) void edge_cos_kernel(
    const int4* __restrict__ sorted, const int* __restrict__ offsets,
    const unsigned short* __restrict__ g, const float* __restrict__ ssq,
    float* __restrict__ out) {
  const int lane = threadIdx.x & 63;
  const int wave = threadIdx.x >> 6;
  const int grp  = blockIdx.x & 7;
  const int wgw  = ((blockIdx.x >> 3) << 2) + wave;   // 0..1023 within group
  const int gs = offsets[grp << 6];
  const int ge = offsets[(grp + 1) << 6];

  for (int e0 = gs + wgw * 4; e0 < ge; e0 += 4096) {
    const int nv = min(4, ge - e0);
    int4 ed[4];
#pragma unroll
    for (int u = 0; u < 4; u++)
      ed[u] = (u < nv) ? sorted[e0 + u] : make_int4(0, 0, 0, 0);

    uint2 va[4], vb[4];
#pragma unroll
    for (int u = 0; u < 4; u++) {
      va[u] = ((const uint2*)(g + (size_t)ed[u].x * H))[lane];
      vb[u] = ((const uint2*)(g + (size_t)ed[u].y * H))[lane];
    }
    float d0, d1, d2, d3;
    float* dp[4] = {&d0, &d1, &d2, &d3};
#pragma unroll
    for (int u = 0; u < 4; u++) {
      uint2 a = va[u], b = vb[u];
      *dp[u] = bflo(a.x) * bflo(b.x) + bfhi(a.x) * bfhi(b.x) +
               bflo(a.y) * bflo(b.y) + bfhi(a.y) * bfhi(b.y);
    }
#pragma unroll
    for (int off = 1; off < 64; off <<= 1) {
      d0 += __shfl_xor(d0, off, 64);
      d1 += __shfl_xor(d1, off, 64);
      d2 += __shfl_xor(d2, off, 64);
      d3 += __shfl_xor(d3, off, 64);
    }
    // 1/max(||g||,eps) = rsqrt(max(ssq, eps^2)); eps=1e-8
    if (lane == 0 && 0 < nv)
      out[ed[0].z] = d0 * rsqrtf(fmaxf(ssq[ed[0].x], 1e-16f)) * rsqrtf(fmaxf(ssq[ed[0].y], 1e-16f));
    if (lane == 1 && 1 < nv)
      out[ed[1].z] = d1 * rsqrtf(fmaxf(ssq[ed[1].x], 1e-16f)) * rsqrtf(fmaxf(ssq[ed[1].y], 1e-16f));
    if (lane == 2 && 2 < nv)
      out[ed[2].z] = d2 * rsqrtf(fmaxf(ssq[ed[2].x], 1e-16f)) * rsqrtf(fmaxf(ssq[ed[2].y], 1e-16f));
    if (lane == 3 && 3 < nv)
      out[ed[3].z] = d3 * rsqrtf(fmaxf(ssq[ed[3].x], 1e-16f)) * rsqrtf(fmaxf(ssq[ed[3].y], 1e-16f));
  }
}

extern "C" void kernel_launch(void* const* d_in, const int* in_sizes, int n_in,
                              void* d_out, int out_size, void* d_ws, size_t ws_size,
                              hipStream_t stream) {
  const float* emb = (const float*)d_in[0];
  const int*   ei  = (const int*)d_in[1];
  const float* W1  = (const float*)d_in[2];
  const float* b1  = (const float*)d_in[3];
  const float* W2  = (const float*)d_in[4];
  const float* b2  = (const float*)d_in[5];
  float* out = (float*)d_out;

  const int NH = in_sizes[0];
  const int N  = NH / H;
  const int E  = in_sizes[1] / 2;
  const int Mp = ((N + 127) / 128) * 128;
  const int MpH = Mp * H;
  const int HH  = H * H;

  char* ws = (char*)d_ws;
  unsigned short* embB = (unsigned short*)ws; ws += (size_t)MpH * 2;
  unsigned short* hB   = (unsigned short*)ws; ws += (size_t)MpH * 2;   // dead after gemm2
  unsigned short* gB   = (unsigned short*)ws; ws += (size_t)MpH * 2;
  unsigned short* w1B  = (unsigned short*)ws; ws += (size_t)HH * 2;
  unsigned short* w2B  = (unsigned short*)ws; ws += (size_t)HH * 2;
  float* ssq           = (float*)ws;          ws += (size_t)Mp * 4;
  int* offsets         = (int*)ws;            ws += (NBINS + 1) * 4;
  int* blockHist       = (int*)ws;            ws += NBINS * NB * 4;
  int* blockCur        = (int*)ws;            ws += NBINS * NB * 4;
  int4* sorted = (int4*)hB;                   // alias: hB dead once gemm2 done

  const int convTotal = (MpH + 2 * HH) / 4;
  conv_all_kernel<<<(convTotal + 255) / 256, 256, 0, stream>>>(
      emb, W1, W2, embB, w1B, w2B, NH, MpH, ssq, Mp);

  dim3 ggrid(Mp / 128, H / 128);
  gemm_bt_kernel<true,  false><<<ggrid, 256, 0, stream>>>(embB, w1B, b1, hB, nullptr);
  gemm_bt_kernel<false, true ><<<ggrid, 256, 0, stream>>>(hB, w2B, b2, gB, ssq);

  hist_kernel<<<NB, 256, 0, stream>>>(ei, E, blockHist);
  scan_kernel<<<1, 512, 0, stream>>>(blockHist, blockCur, offsets);
  scatter_kernel<<<NB, 256, 0, stream>>>(ei, E, blockCur, sorted);

  edge_cos_kernel<<<2048, 256, 0, stream>>>(sorted, offsets, gB, ssq, out);
}

// Round 4
// 241.476 us; speedup vs baseline: 1.2384x; 1.1828x over previous
//
#include <hip/hip_runtime.h>
#include <stdint.h>

#define H 256
#define NBINS 512          // skey space: (bucket&7)<<6 | bucket>>3, bucket = c>>7 < 392
#define NB 128             // blocks in hist/scatter (each owns E/NB contiguous edges)
#define SCAN_T 1024        // threads in scan kernel; each owns NBINS*NB/SCAN_T = 64 ints

typedef __bf16 bf16x8 __attribute__((ext_vector_type(8)));
typedef float  f32x4  __attribute__((ext_vector_type(4)));

__device__ __forceinline__ unsigned short f2bf(float f) {
  unsigned u = __builtin_bit_cast(unsigned, f);
  u += 0x7FFFu + ((u >> 16) & 1u);            // round-to-nearest-even
  return (unsigned short)(u >> 16);
}
__device__ __forceinline__ float bflo(unsigned u){ return __builtin_bit_cast(float, u << 16); }
__device__ __forceinline__ float bfhi(unsigned u){ return __builtin_bit_cast(float, u & 0xFFFF0000u); }

__device__ __forceinline__ void g2l16(const void* g, void* l) {
  __builtin_amdgcn_global_load_lds((__attribute__((address_space(1))) void*)g,
                                   (__attribute__((address_space(3))) void*)l, 16, 0, 0);
}

__device__ __forceinline__ int skey_of(int c) {
  int b = c >> 7;
  return ((b & 7) << 6) | (b >> 3);
}

// fp32 -> bf16 for emb (zero-padded to Mp rows), W1, W2 in ONE launch.
// Also zeroes ssq[] (accumulated by gemm2's epilogue later in the stream).
__global__ __launch_bounds__(256) void conv_all_kernel(
    const float* __restrict__ emb, const float* __restrict__ W1, const float* __restrict__ W2,
    unsigned short* __restrict__ embB, unsigned short* __restrict__ w1B,
    unsigned short* __restrict__ w2B, int NH, int MpH, float* __restrict__ ssq, int Mp) {
  int t = blockIdx.x * 256 + threadIdx.x;
  if (t < Mp) ssq[t] = 0.f;
  int i = t * 4;
  const int HH = H * H;
  const float* src; unsigned short* dst; int idx; int valid;
  if (i < MpH)            { src = emb; dst = embB; idx = i;            valid = NH; }
  else if (i < MpH + HH)  { src = W1;  dst = w1B;  idx = i - MpH;      valid = HH; }
  else                    { src = W2;  dst = w2B;  idx = i - MpH - HH; valid = HH; }
  float4 v = make_float4(0.f, 0.f, 0.f, 0.f);
  if (idx < valid) v = *(const float4*)(src + idx);
  ushort4 o;
  o.x = f2bf(v.x); o.y = f2bf(v.y); o.z = f2bf(v.z); o.w = f2bf(v.w);
  *(ushort4*)(dst + idx) = o;
}

// C[Mp,256] = act(A[Mp,256] @ B[256,256]^T + bias), bf16 in/out, fp32 accum.
// NORM: atomically accumulate per-row sum-of-squares of the outputs.
template<bool RELU, bool NORM>
__global__ __launch_bounds__(256) void gemm_bt_kernel(
    const unsigned short* __restrict__ A,
    const unsigned short* __restrict__ B,
    const float* __restrict__ bias,
    unsigned short* __restrict__ C,
    float* __restrict__ ssq) {
  __shared__ unsigned short sA[128 * 32];
  __shared__ unsigned short sB[128 * 32];
  const int tid  = threadIdx.x;
  const int wave = tid >> 6, lane = tid & 63;
  const int quad = lane >> 4, l16 = lane & 15;
  const int wm = wave & 1, wn = wave >> 1;
  const size_t bm = blockIdx.x, bn = blockIdx.y;

  const int srow0 = (wave * 2 + 0) * 16 + (lane >> 2);
  const int srow1 = (wave * 2 + 1) * 16 + (lane >> 2);
  const int kch   = (lane & 3) * 8;
  const unsigned short* gA0 = A + ((bm * 128 + srow0) * H + kch);
  const unsigned short* gA1 = A + ((bm * 128 + srow1) * H + kch);
  const unsigned short* gB0 = B + ((bn * 128 + srow0) * H + kch);
  const unsigned short* gB1 = B + ((bn * 128 + srow1) * H + kch);
  unsigned short* lA0 = sA + (wave * 2 + 0) * 512 + lane * 8;
  unsigned short* lA1 = sA + (wave * 2 + 1) * 512 + lane * 8;
  unsigned short* lB0 = sB + (wave * 2 + 0) * 512 + lane * 8;
  unsigned short* lB1 = sB + (wave * 2 + 1) * 512 + lane * 8;

  f32x4 acc[4][4];
#pragma unroll
  for (int i = 0; i < 4; i++)
#pragma unroll
    for (int j = 0; j < 4; j++) acc[i][j] = (f32x4){0.f, 0.f, 0.f, 0.f};

#pragma unroll
  for (int kk = 0; kk < H / 32; ++kk) {
    const int k0 = kk * 32;
    if (kk) __syncthreads();
    g2l16(gA0 + k0, lA0);
    g2l16(gA1 + k0, lA1);
    g2l16(gB0 + k0, lB0);
    g2l16(gB1 + k0, lB1);
    __syncthreads();

    bf16x8 af[4], bfr[4];
#pragma unroll
    for (int i = 0; i < 4; i++)
      af[i] = *(const bf16x8*)(sA + ((wm * 64 + i * 16 + l16) * 32 + quad * 8));
#pragma unroll
    for (int j = 0; j < 4; j++)
      bfr[j] = *(const bf16x8*)(sB + ((wn * 64 + j * 16 + l16) * 32 + quad * 8));
#pragma unroll
    for (int i = 0; i < 4; i++)
#pragma unroll
      for (int j = 0; j < 4; j++)
        acc[i][j] = __builtin_amdgcn_mfma_f32_16x16x32_bf16(af[i], bfr[j], acc[i][j], 0, 0, 0);
  }

  // epilogue: C/D layout col=lane&15, row=quad*4+reg (m89/m91-verified)
  const int row_base = (int)bm * 128 + wm * 64;
  const int col_base = (int)bn * 128 + wn * 64;
  float p[4][4];
  if (NORM) {
#pragma unroll
    for (int i = 0; i < 4; i++)
#pragma unroll
      for (int r = 0; r < 4; r++) p[i][r] = 0.f;
  }
#pragma unroll
  for (int j = 0; j < 4; j++) {
    const int col = col_base + j * 16 + l16;
    const float bv = bias[col];
#pragma unroll
    for (int i = 0; i < 4; i++) {
#pragma unroll
      for (int r = 0; r < 4; r++) {
        const int row = row_base + i * 16 + quad * 4 + r;
        float v = acc[i][j][r] + bv;
        if (RELU) v = fmaxf(v, 0.f);
        if (NORM) p[i][r] += v * v;
        C[(size_t)row * H + col] = f2bf(v);
      }
    }
  }
  if (NORM) {
#pragma unroll
    for (int i = 0; i < 4; i++) {
#pragma unroll
      for (int r = 0; r < 4; r++) {
        float s = p[i][r];
#pragma unroll
        for (int off = 1; off < 16; off <<= 1) s += __shfl_xor(s, off, 64);
        if (l16 == 0) atomicAdd(&ssq[row_base + i * 16 + quad * 4 + r], s);
      }
    }
  }
}

// ---- deterministic counting-sort: LDS hist -> parallel scan -> LDS-cursor scatter ----
__global__ __launch_bounds__(256) void hist_kernel(
    const int* __restrict__ ei, int E, int* __restrict__ blockHist) {
  __shared__ int h[NBINS];
  for (int i = threadIdx.x; i < NBINS; i += 256) h[i] = 0;
  __syncthreads();
  const int chunk = (E + NB - 1) / NB;
  const int start = blockIdx.x * chunk, end = min(E, start + chunk);
  for (int e = start + threadIdx.x; e < end; e += 256)
    atomicAdd(&h[skey_of(ei[e])], 1);
  __syncthreads();
  for (int i = threadIdx.x; i < NBINS; i += 256)
    blockHist[i * NB + blockIdx.x] = h[i];
}

// Two-pass parallel exclusive scan over the flat [NBINS*NB] histogram.
// Thread t owns flat [t*64, t*64+64): pass1 sums via independent int4 loads,
// Hillis-Steele over 1024 thread-sums in LDS, pass2 re-reads + writes prefixes.
__global__ __launch_bounds__(SCAN_T) void scan_kernel(
    const int* __restrict__ blockHist, int* __restrict__ blockCur,
    int* __restrict__ offsets) {
  __shared__ int s[SCAN_T];
  const int t = threadIdx.x;
  const int PER = NBINS * NB / SCAN_T;         // 64
  const int base = t * PER;
  int sum = 0;
#pragma unroll
  for (int j = 0; j < PER; j += 4) {
    int4 v = *(const int4*)(blockHist + base + j);
    sum += v.x + v.y + v.z + v.w;
  }
  s[t] = sum;
  __syncthreads();
#pragma unroll
  for (int d = 1; d < SCAN_T; d <<= 1) {
    int v = (t >= d) ? s[t - d] : 0;
    __syncthreads();
    s[t] += v;
    __syncthreads();
  }
  int run = s[t] - sum;                        // exclusive base for this thread
  if (t == SCAN_T - 1) offsets[NBINS] = s[t];
  // bin boundaries (flat index multiple of NB=128) align to even threads (PER=64)
  if ((base % NB) == 0) offsets[base / NB] = run;
#pragma unroll
  for (int j = 0; j < PER; j += 4) {
    int4 v = *(const int4*)(blockHist + base + j);
    int4 o;
    o.x = run; run += v.x;
    o.y = run; run += v.y;
    o.z = run; run += v.z;
    o.w = run; run += v.w;
    *(int4*)(blockCur + base + j) = o;
  }
}

__global__ __launch_bounds__(256) void scatter_kernel(
    const int* __restrict__ ei, int E, const int* __restrict__ blockCur,
    int4* __restrict__ sorted) {
  __shared__ int cur[NBINS];
  for (int i = threadIdx.x; i < NBINS; i += 256)
    cur[i] = blockCur[i * NB + blockIdx.x];
  __syncthreads();
  const int chunk = (E + NB - 1) / NB;
  const int start = blockIdx.x * chunk, end = min(E, start + chunk);
  for (int e = start + threadIdx.x; e < end; e += 256) {
    int c = ei[e], r = ei[E + e];
    int pos = atomicAdd(&cur[skey_of(c)], 1);   // LDS atomic; disjoint ranges per block
    sorted[pos] = make_int4(c, r, e, 0);
  }
}

// one wave per 4 edges; blockIdx%8 == XCD-group -> c-side rows stay L2-resident
__global__ __launch_bounds__(256) void edge_cos_kernel(
    const int4* __restrict__ sorted, const int* __restrict__ offsets,
    const unsigned short* __restrict__ g, const float* __restrict__ ssq,
    float* __restrict__ out) {
  const int lane = threadIdx.x & 63;
  const int wave = threadIdx.x >> 6;
  const int grp  = blockIdx.x & 7;
  const int wgw  = ((blockIdx.x >> 3) << 2) + wave;   // 0..1023 within group
  const int gs = offsets[grp << 6];
  const int ge = offsets[(grp + 1) << 6];

  for (int e0 = gs + wgw * 4; e0 < ge; e0 += 4096) {
    const int nv = min(4, ge - e0);
    int4 ed[4];
#pragma unroll
    for (int u = 0; u < 4; u++)
      ed[u] = (u < nv) ? sorted[e0 + u] : make_int4(0, 0, 0, 0);

    uint2 va[4], vb[4];
#pragma unroll
    for (int u = 0; u < 4; u++) {
      va[u] = ((const uint2*)(g + (size_t)ed[u].x * H))[lane];
      vb[u] = ((const uint2*)(g + (size_t)ed[u].y * H))[lane];
    }
    float d0, d1, d2, d3;
    float* dp[4] = {&d0, &d1, &d2, &d3};
#pragma unroll
    for (int u = 0; u < 4; u++) {
      uint2 a = va[u], b = vb[u];
      *dp[u] = bflo(a.x) * bflo(b.x) + bfhi(a.x) * bfhi(b.x) +
               bflo(a.y) * bflo(b.y) + bfhi(a.y) * bfhi(b.y);
    }
#pragma unroll
    for (int off = 1; off < 64; off <<= 1) {
      d0 += __shfl_xor(d0, off, 64);
      d1 += __shfl_xor(d1, off, 64);
      d2 += __shfl_xor(d2, off, 64);
      d3 += __shfl_xor(d3, off, 64);
    }
    if (lane == 0 && 0 < nv)
      out[ed[0].z] = d0 * rsqrtf(fmaxf(ssq[ed[0].x], 1e-16f)) * rsqrtf(fmaxf(ssq[ed[0].y], 1e-16f));
    if (lane == 1 && 1 < nv)
      out[ed[1].z] = d1 * rsqrtf(fmaxf(ssq[ed[1].x], 1e-16f)) * rsqrtf(fmaxf(ssq[ed[1].y], 1e-16f));
    if (lane == 2 && 2 < nv)
      out[ed[2].z] = d2 * rsqrtf(fmaxf(ssq[ed[2].x], 1e-16f)) * rsqrtf(fmaxf(ssq[ed[2].y], 1e-16f));
    if (lane == 3 && 3 < nv)
      out[ed[3].z] = d3 * rsqrtf(fmaxf(ssq[ed[3].x], 1e-16f)) * rsqrtf(fmaxf(ssq[ed[3].y], 1e-16f));
  }
}

extern "C" void kernel_launch(void* const* d_in, const int* in_sizes, int n_in,
                              void* d_out, int out_size, void* d_ws, size_t ws_size,
                              hipStream_t stream) {
  const float* emb = (const float*)d_in[0];
  const int*   ei  = (const int*)d_in[1];
  const float* W1  = (const float*)d_in[2];
  const float* b1  = (const float*)d_in[3];
  const float* W2  = (const float*)d_in[4];
  const float* b2  = (const float*)d_in[5];
  float* out = (float*)d_out;

  const int NH = in_sizes[0];
  const int N  = NH / H;
  const int E  = in_sizes[1] / 2;
  const int Mp = ((N + 127) / 128) * 128;
  const int MpH = Mp * H;
  const int HH  = H * H;

  char* ws = (char*)d_ws;
  unsigned short* embB = (unsigned short*)ws; ws += (size_t)MpH * 2;
  unsigned short* hB   = (unsigned short*)ws; ws += (size_t)MpH * 2;   // dead after gemm2
  unsigned short* gB   = (unsigned short*)ws; ws += (size_t)MpH * 2;
  unsigned short* w1B  = (unsigned short*)ws; ws += (size_t)HH * 2;
  unsigned short* w2B  = (unsigned short*)ws; ws += (size_t)HH * 2;
  float* ssq           = (float*)ws;          ws += (size_t)Mp * 4;
  int* offsets         = (int*)ws;            ws += (NBINS + 1) * 4;
  int* blockHist       = (int*)ws;            ws += NBINS * NB * 4;
  int* blockCur        = (int*)ws;            ws += NBINS * NB * 4;
  int4* sorted = (int4*)hB;                   // alias: hB dead once gemm2 done

  const int convTotal = (MpH + 2 * HH) / 4;
  conv_all_kernel<<<(convTotal + 255) / 256, 256, 0, stream>>>(
      emb, W1, W2, embB, w1B, w2B, NH, MpH, ssq, Mp);

  dim3 ggrid(Mp / 128, H / 128);
  gemm_bt_kernel<true,  false><<<ggrid, 256, 0, stream>>>(embB, w1B, b1, hB, nullptr);
  gemm_bt_kernel<false, true ><<<ggrid, 256, 0, stream>>>(hB, w2B, b2, gB, ssq);

  hist_kernel<<<NB, 256, 0, stream>>>(ei, E, blockHist);
  scan_kernel<<<1, SCAN_T, 0, stream>>>(blockHist, blockCur, offsets);
  scatter_kernel<<<NB, 256, 0, stream>>>(ei, E, blockCur, sorted);

  edge_cos_kernel<<<2048, 256, 0, stream>>>(sorted, offsets, gB, ssq, out);
}